// Round 1
// baseline (547.577 us; speedup 1.0000x reference)
//
#include <hip/hip_runtime.h>

// out[token, :] = W[:, ids[token]]   (gather columns of W)
// W: [D_MODEL, VOCAB] row-major fp32; ids: int32 [B*S]; out: [B*S, D_MODEL] fp32.
#define VOCAB  50257
#define DMODEL 1024

__global__ __launch_bounds__(256) void gather_cols_kernel(
    const int* __restrict__ ids,
    const float* __restrict__ W,
    float* __restrict__ out,
    int n_tokens)
{
    const int token = blockIdx.x;
    if (token >= n_tokens) return;

    // Wave-uniform load -> compiler emits s_load; broadcast to all lanes.
    const int id = ids[token];

    // Each thread produces 4 consecutive d-values -> one float4 store.
    const int d0 = threadIdx.x << 2;                 // 0..1020
    const size_t base = (size_t)d0 * VOCAB + (size_t)id;

    // 4 independent scattered loads (each on its own cache line; stride ~201KB).
    float4 v;
    v.x = W[base];
    v.y = W[base + (size_t)VOCAB];
    v.z = W[base + (size_t)(2 * VOCAB)];
    v.w = W[base + (size_t)(3 * VOCAB)];

    // Coalesced 16B/lane store: out[token*1024 + d0 .. d0+3]
    reinterpret_cast<float4*>(out + (size_t)token * DMODEL)[threadIdx.x] = v;
}

extern "C" void kernel_launch(void* const* d_in, const int* in_sizes, int n_in,
                              void* d_out, int out_size, void* d_ws, size_t ws_size,
                              hipStream_t stream) {
    const int*   ids = (const int*)d_in[0];    // [B*S] = 16384 int32
    const float* W   = (const float*)d_in[1];  // [1024, 50257] fp32
    float*       out = (float*)d_out;          // [16384, 1024] fp32

    const int n_tokens = in_sizes[0];          // 16384
    gather_cols_kernel<<<n_tokens, DMODEL / 4, 0, stream>>>(ids, W, out, n_tokens);
}

// Round 3
// 339.858 us; speedup vs baseline: 1.6112x; 1.6112x over previous
//
#include <hip/hip_runtime.h>
#include <stdint.h>

// out[t, :] = W[:, ids[t]]
// W: [DMODEL, VOCAB] row-major fp32. Strategy: loop inversion.
// Bucket tokens by vocab window of 256, then stream W coalesced exactly once:
// each block loads a 64x256 W tile to LDS and emits 64 d-values for every
// token whose id falls in its window. Total traffic ~272 MB vs 1.03 GB for
// the naive gather (measured round 1: FETCH_SIZE=1.03GB, 340us).
#define VOCAB   50257
#define DMODEL  1024
#define VWIN    256                    // vocab window per bucket
#define NB      ((VOCAB + VWIN - 1) / VWIN)   // 197 buckets
#define DCHUNK  64

// ws layout (int32 elements) — regions sized so scan's 257 writes fit:
//   [0..255]      count   (only 0..196 used)
//   [256..767]    start   (scan writes indices 256..512 — 512-wide region)
//   [768..1023]   cursor
//   [1024..]      perm    (n_tokens entries, packed (id<<16)|t)
// Total: (1024 + 16384) * 4 = 69,632 bytes of d_ws.
#define WS_COUNT   0
#define WS_START   256
#define WS_CURSOR  768
#define WS_PERM    1024

__global__ __launch_bounds__(256) void hist_kernel(
    const int* __restrict__ ids, int* __restrict__ ws, int n_tokens)
{
    int t = blockIdx.x * 256 + threadIdx.x;
    if (t < n_tokens) {
        int id = ids[t];
        atomicAdd(&ws[WS_COUNT + (id >> 8)], 1);
    }
}

__global__ __launch_bounds__(256) void scan_kernel(int* __restrict__ ws)
{
    __shared__ int s[256];
    int tid = threadIdx.x;
    int c = (tid < NB) ? ws[WS_COUNT + tid] : 0;
    s[tid] = c;
    __syncthreads();
    // Hillis-Steele inclusive scan over 256 entries
    for (int off = 1; off < 256; off <<= 1) {
        int v = (tid >= off) ? s[tid - off] : 0;
        __syncthreads();
        s[tid] += v;
        __syncthreads();
    }
    if (tid == 0) ws[WS_START + 0] = 0;
    ws[WS_START + tid + 1] = s[tid];   // writes 257..512, inside 512-wide region
}

__global__ __launch_bounds__(256) void scatter_kernel(
    const int* __restrict__ ids, int* __restrict__ ws, int n_tokens)
{
    int t = blockIdx.x * 256 + threadIdx.x;
    if (t < n_tokens) {
        int id = ids[t];
        int b  = id >> 8;
        int pos = ws[WS_START + b] + atomicAdd(&ws[WS_CURSOR + b], 1);
        ws[WS_PERM + pos] = (int)(((uint32_t)id << 16) | (uint32_t)t);
    }
}

__global__ __launch_bounds__(256) void emit_kernel(
    const float* __restrict__ W, const int* __restrict__ ws,
    float* __restrict__ out)
{
    __shared__ float tile[DCHUNK][VWIN + 1];   // pad -> conflict-free col reads

    const int vwin = blockIdx.x;          // 0..196
    const int d0   = blockIdx.y << 6;     // 0..960 step 64
    const int v0   = vwin << 8;
    const int tid  = threadIdx.x;

    // ---- Stage W tile [d0..d0+63] x [v0..v0+255], coalesced float4 ----
    const float* Wbase = W + (size_t)d0 * VOCAB + v0;
    const int limit = VOCAB - v0;         // valid cols: < limit
    if (limit >= VWIN) {
        for (int e = tid * 4; e < DCHUNK * VWIN; e += 256 * 4) {
            int r = e >> 8, c = e & 255;
            float4 v = *(const float4*)(Wbase + (size_t)r * VOCAB + c);
            tile[r][c]     = v.x;
            tile[r][c + 1] = v.y;
            tile[r][c + 2] = v.z;
            tile[r][c + 3] = v.w;
        }
    } else {
        for (int e = tid * 4; e < DCHUNK * VWIN; e += 256 * 4) {
            int r = e >> 8, c = e & 255;
#pragma unroll
            for (int j = 0; j < 4; j++)
                tile[r][c + j] = (c + j < limit)
                    ? Wbase[(size_t)r * VOCAB + c + j] : 0.0f;
        }
    }
    __syncthreads();

    // ---- Emit: each wave handles one token per iteration ----
    const int begin = ws[WS_START + vwin];
    const int end   = ws[WS_START + vwin + 1];
    const int lane  = tid & 63;           // = d offset within chunk
    const int w     = tid >> 6;           // wave id, 0..3

    for (int i = begin + w; i < end; i += 4) {
        uint32_t packed = (uint32_t)ws[WS_PERM + i];
        int t   = (int)(packed & 0xFFFFu);
        int col = (int)(packed >> 16) - v0;
        // conflict-free: bank = (257*lane + col) % 32 = (lane + col) % 32
        out[(size_t)t * DMODEL + d0 + lane] = tile[lane][col];
    }
}

extern "C" void kernel_launch(void* const* d_in, const int* in_sizes, int n_in,
                              void* d_out, int out_size, void* d_ws, size_t ws_size,
                              hipStream_t stream) {
    const int*   ids = (const int*)d_in[0];    // [B*S] = 16384
    const float* W   = (const float*)d_in[1];  // [1024, 50257]
    float*       out = (float*)d_out;
    int*         ws  = (int*)d_ws;

    const int n_tokens = in_sizes[0];
    const int nblk = (n_tokens + 255) / 256;

    // zero count + start + cursor (first 1024 ints)
    hipMemsetAsync(ws, 0, 1024 * sizeof(int), stream);
    hist_kernel<<<nblk, 256, 0, stream>>>(ids, ws, n_tokens);
    scan_kernel<<<1, 256, 0, stream>>>(ws);
    scatter_kernel<<<nblk, 256, 0, stream>>>(ids, ws, n_tokens);

    dim3 grid(NB, DMODEL / DCHUNK);   // 197 x 16
    emit_kernel<<<grid, 256, 0, stream>>>(W, ws, out);
}

// Round 4
// 334.526 us; speedup vs baseline: 1.6369x; 1.0159x over previous
//
#include <hip/hip_runtime.h>
#include <stdint.h>

// out[t, :] = W[:, ids[t]]
// W: [DMODEL, VOCAB] row-major fp32. Loop inversion: bucket tokens by vocab
// window of 256, stream W coalesced exactly once through LDS tiles, emit
// per-token rows. Round 3 measured pipeline ~132us (emit ~120us) at 2 blocks/CU.
// Round 4: DCHUNK 64->32 (4 blocks/CU) + float4 stores (8 tokens/wave-iter).
#define VOCAB   50257
#define DMODEL  1024
#define VWIN    256
#define NB      ((VOCAB + VWIN - 1) / VWIN)   // 197 buckets
#define DCHUNK  32                            // 32x257x4 = 32.9 KB LDS -> 4 blocks/CU

// ws layout (int32 elements):
//   [0..255]      count
//   [256..767]    start   (scan writes 256..512)
//   [768..1023]   cursor
//   [1024..]      perm    (packed (id<<16)|t)
#define WS_COUNT   0
#define WS_START   256
#define WS_CURSOR  768
#define WS_PERM    1024

__global__ __launch_bounds__(256) void hist_kernel(
    const int* __restrict__ ids, int* __restrict__ ws, int n_tokens)
{
    int t = blockIdx.x * 256 + threadIdx.x;
    if (t < n_tokens) {
        int id = ids[t];
        atomicAdd(&ws[WS_COUNT + (id >> 8)], 1);
    }
}

__global__ __launch_bounds__(256) void scan_kernel(int* __restrict__ ws)
{
    __shared__ int s[256];
    int tid = threadIdx.x;
    int c = (tid < NB) ? ws[WS_COUNT + tid] : 0;
    s[tid] = c;
    __syncthreads();
    for (int off = 1; off < 256; off <<= 1) {
        int v = (tid >= off) ? s[tid - off] : 0;
        __syncthreads();
        s[tid] += v;
        __syncthreads();
    }
    if (tid == 0) ws[WS_START + 0] = 0;
    ws[WS_START + tid + 1] = s[tid];   // writes 257..512, inside region
}

__global__ __launch_bounds__(256) void scatter_kernel(
    const int* __restrict__ ids, int* __restrict__ ws, int n_tokens)
{
    int t = blockIdx.x * 256 + threadIdx.x;
    if (t < n_tokens) {
        int id = ids[t];
        int b  = id >> 8;
        int pos = ws[WS_START + b] + atomicAdd(&ws[WS_CURSOR + b], 1);
        ws[WS_PERM + pos] = (int)(((uint32_t)id << 16) | (uint32_t)t);
    }
}

__global__ __launch_bounds__(256) void emit_kernel(
    const float* __restrict__ W, const int* __restrict__ ws,
    float* __restrict__ out)
{
    __shared__ float tile[DCHUNK][VWIN + 1];   // stride 257 -> conflict-light

    const int vwin = blockIdx.x;          // 0..196
    const int d0   = blockIdx.y * DCHUNK; // 0..992 step 32
    const int v0   = vwin << 8;
    const int tid  = threadIdx.x;

    // ---- Stage W tile [d0..d0+31] x [v0..v0+255], coalesced float4 ----
    const float* Wbase = W + (size_t)d0 * VOCAB + v0;
    const int limit = VOCAB - v0;         // valid cols: < limit
    if (limit >= VWIN) {
        for (int e = tid * 4; e < DCHUNK * VWIN; e += 256 * 4) {
            int r = e >> 8, c = e & 255;
            float4 v = *(const float4*)(Wbase + (size_t)r * VOCAB + c);
            tile[r][c]     = v.x;
            tile[r][c + 1] = v.y;
            tile[r][c + 2] = v.z;
            tile[r][c + 3] = v.w;
        }
    } else {
        for (int e = tid * 4; e < DCHUNK * VWIN; e += 256 * 4) {
            int r = e >> 8, c = e & 255;
#pragma unroll
            for (int j = 0; j < 4; j++)
                tile[r][c + j] = (c + j < limit)
                    ? Wbase[(size_t)r * VOCAB + c + j] : 0.0f;
        }
    }
    __syncthreads();

    // ---- Emit: 8 tokens per wave-iteration, 8 lanes x float4 per token ----
    const int begin = ws[WS_START + vwin];
    const int end   = ws[WS_START + vwin + 1];
    const int lane  = tid & 63;
    const int w     = tid >> 6;           // wave id, 0..3
    const int g     = lane >> 3;          // token slot within wave, 0..7
    const int dsub  = (lane & 7) << 2;    // d offset 0,4,..,28

    for (int i = begin + w * 8; i < end; i += 32) {
        int idx = i + g;
        if (idx < end) {
            uint32_t packed = (uint32_t)ws[WS_PERM + idx];
            int t   = (int)(packed & 0xFFFFu);
            int col = (int)(packed >> 16) - v0;
            float4 v;
            v.x = tile[dsub][col];
            v.y = tile[dsub + 1][col];
            v.z = tile[dsub + 2][col];
            v.w = tile[dsub + 3][col];
            // 128B line-aligned segment per token
            *(float4*)(out + (size_t)t * DMODEL + d0 + dsub) = v;
        }
    }
}

extern "C" void kernel_launch(void* const* d_in, const int* in_sizes, int n_in,
                              void* d_out, int out_size, void* d_ws, size_t ws_size,
                              hipStream_t stream) {
    const int*   ids = (const int*)d_in[0];    // [B*S] = 16384
    const float* W   = (const float*)d_in[1];  // [1024, 50257]
    float*       out = (float*)d_out;
    int*         ws  = (int*)d_ws;

    const int n_tokens = in_sizes[0];
    const int nblk = (n_tokens + 255) / 256;

    hipMemsetAsync(ws, 0, 1024 * sizeof(int), stream);
    hist_kernel<<<nblk, 256, 0, stream>>>(ids, ws, n_tokens);
    scan_kernel<<<1, 256, 0, stream>>>(ws);
    scatter_kernel<<<nblk, 256, 0, stream>>>(ids, ws, n_tokens);

    dim3 grid(NB, DMODEL / DCHUNK);   // 197 x 32
    emit_kernel<<<grid, 256, 0, stream>>>(W, ws, out);
}

// Round 5
// 320.140 us; speedup vs baseline: 1.7104x; 1.0449x over previous
//
#include <hip/hip_runtime.h>
#include <stdint.h>

// out[t, :] = W[:, ids[t]]
// Loop inversion: bucket tokens by vocab window of 256, stream W coalesced
// exactly once through LDS tiles, emit per-token rows.
// Round 5: eliminate ALL global atomics (round-4 evidence: emit-side opts
// moved bench only -6us => hist/scatter's 2x16384 contended atomics on ~7
// cache lines are the hidden cost). Hierarchical: per-block LDS histograms,
// deterministic 197x16 scan, LDS-cursor scatter.
#define VOCAB   50257
#define DMODEL  1024
#define VWIN    256
#define NB      ((VOCAB + VWIN - 1) / VWIN)   // 197
#define DCHUNK  32                            // 32x257x4 = 32.9 KB LDS
#define HBLK    16                            // histogram/scatter blocks
#define NTOT    (NB * HBLK)                   // 3152 count slots

// ws layout (int32):
//   [0..4095]      counts[bucket*16 + blk]   (each slot written once; no memset)
//   [4096..8191]   start — exclusive scan of counts, NTOT+1 entries used
//   [8192..]       perm  — packed (id<<16)|t, grouped by bucket
#define WS_COUNT  0
#define WS_START  4096
#define WS_PERM   8192

__global__ __launch_bounds__(256) void hist_kernel(
    const int* __restrict__ ids, int* __restrict__ ws, int n_tokens)
{
    __shared__ int h[NB];
    const int tid = threadIdx.x, blk = blockIdx.x;
    for (int i = tid; i < NB; i += 256) h[i] = 0;
    __syncthreads();
    const int per = (n_tokens + HBLK - 1) / HBLK;
    const int t0 = blk * per;
    const int t1 = min(n_tokens, t0 + per);
    for (int t = t0 + tid; t < t1; t += 256)
        atomicAdd(&h[ids[t] >> 8], 1);            // LDS atomic
    __syncthreads();
    for (int i = tid; i < NB; i += 256)
        ws[WS_COUNT + i * HBLK + blk] = h[i];     // plain store, slot unique
}

__global__ __launch_bounds__(256) void scan_kernel(int* __restrict__ ws)
{
    __shared__ int s[256];
    const int tid = threadIdx.x;
    const int CH = (NTOT + 255) / 256;            // 13
    const int base = tid * CH;
    int vals[(NTOT + 255) / 256];
    int sum = 0;
#pragma unroll
    for (int j = 0; j < CH; j++) {
        int idx = base + j;
        int v = (idx < NTOT) ? ws[WS_COUNT + idx] : 0;
        vals[j] = v; sum += v;
    }
    s[tid] = sum;
    __syncthreads();
    for (int off = 1; off < 256; off <<= 1) {
        int v = (tid >= off) ? s[tid - off] : 0;
        __syncthreads();
        s[tid] += v;
        __syncthreads();
    }
    int run = (tid > 0) ? s[tid - 1] : 0;         // exclusive prefix
#pragma unroll
    for (int j = 0; j < CH; j++) {
        int idx = base + j;
        if (idx < NTOT) ws[WS_START + idx] = run;
        run += vals[j];
    }
    if (tid == 255) ws[WS_START + NTOT] = run;    // total
}

__global__ __launch_bounds__(256) void scatter_kernel(
    const int* __restrict__ ids, int* __restrict__ ws, int n_tokens)
{
    __shared__ int cur[NB];
    const int tid = threadIdx.x, blk = blockIdx.x;
    for (int i = tid; i < NB; i += 256)
        cur[i] = ws[WS_START + i * HBLK + blk];   // this block's range starts
    __syncthreads();
    const int per = (n_tokens + HBLK - 1) / HBLK;
    const int t0 = blk * per;
    const int t1 = min(n_tokens, t0 + per);
    for (int t = t0 + tid; t < t1; t += 256) {
        int id = ids[t];
        int b  = id >> 8;
        int pos = atomicAdd(&cur[b], 1);          // LDS atomic
        ws[WS_PERM + pos] = (int)(((uint32_t)id << 16) | (uint32_t)t);
    }
}

__global__ __launch_bounds__(256) void emit_kernel(
    const float* __restrict__ W, const int* __restrict__ ws,
    float* __restrict__ out)
{
    __shared__ float tile[DCHUNK][VWIN + 1];

    const int vwin = blockIdx.x;          // 0..196
    const int d0   = blockIdx.y * DCHUNK; // 0..992 step 32
    const int v0   = vwin << 8;
    const int tid  = threadIdx.x;

    // ---- Stage W tile [d0..d0+31] x [v0..v0+255], coalesced float4 ----
    const float* Wbase = W + (size_t)d0 * VOCAB + v0;
    const int limit = VOCAB - v0;
    if (limit >= VWIN) {
        for (int e = tid * 4; e < DCHUNK * VWIN; e += 256 * 4) {
            int r = e >> 8, c = e & 255;
            float4 v = *(const float4*)(Wbase + (size_t)r * VOCAB + c);
            tile[r][c]     = v.x;
            tile[r][c + 1] = v.y;
            tile[r][c + 2] = v.z;
            tile[r][c + 3] = v.w;
        }
    } else {
        for (int e = tid * 4; e < DCHUNK * VWIN; e += 256 * 4) {
            int r = e >> 8, c = e & 255;
#pragma unroll
            for (int j = 0; j < 4; j++)
                tile[r][c + j] = (c + j < limit)
                    ? Wbase[(size_t)r * VOCAB + c + j] : 0.0f;
        }
    }
    __syncthreads();

    // ---- Emit: 8 tokens per wave-iteration, 8 lanes x float4 per token ----
    const int begin = ws[WS_START + vwin * HBLK];
    const int end   = ws[WS_START + (vwin + 1) * HBLK];
    const int lane  = tid & 63;
    const int w     = tid >> 6;
    const int g     = lane >> 3;          // token slot in wave, 0..7
    const int dsub  = (lane & 7) << 2;    // d offset 0,4,..,28

    for (int i = begin + w * 8; i < end; i += 32) {
        int idx = i + g;
        if (idx < end) {
            uint32_t packed = (uint32_t)ws[WS_PERM + idx];
            int t   = (int)(packed & 0xFFFFu);
            int col = (int)(packed >> 16) - v0;
            float4 v;
            v.x = tile[dsub][col];
            v.y = tile[dsub + 1][col];
            v.z = tile[dsub + 2][col];
            v.w = tile[dsub + 3][col];
            *(float4*)(out + (size_t)t * DMODEL + d0 + dsub) = v;
        }
    }
}

extern "C" void kernel_launch(void* const* d_in, const int* in_sizes, int n_in,
                              void* d_out, int out_size, void* d_ws, size_t ws_size,
                              hipStream_t stream) {
    const int*   ids = (const int*)d_in[0];    // [B*S] = 16384
    const float* W   = (const float*)d_in[1];  // [1024, 50257]
    float*       out = (float*)d_out;
    int*         ws  = (int*)d_ws;

    const int n_tokens = in_sizes[0];

    hist_kernel<<<HBLK, 256, 0, stream>>>(ids, ws, n_tokens);
    scan_kernel<<<1, 256, 0, stream>>>(ws);
    scatter_kernel<<<HBLK, 256, 0, stream>>>(ids, ws, n_tokens);

    dim3 grid(NB, DMODEL / DCHUNK);   // 197 x 32
    emit_kernel<<<grid, 256, 0, stream>>>(W, ws, out);
}